// Round 4
// baseline (301.909 us; speedup 1.0000x reference)
//
#include <hip/hip_runtime.h>
#include <math.h>

// Problem constants (match reference)
constexpr int D    = 64;   // input feature dim
constexpr int H    = 14;   // hidden dim (2*LAT)
constexpr int HP   = 16;   // padded feature stride (64B rows)
constexpr int P    = 16;   // (LAT+1)*R
constexpr int LATc = 7;
constexpr int OUTW = 30;   // 7 + 7 + 14 + 2
constexpr float SP_INV_1 = 0.5413248546129181f; // log(expm1(1))

// ---------------- Dense: XW = X @ W1 (padded to 16), (N,64)@(64,14) -------
__global__ void dense_xw_kernel(const float* __restrict__ X,
                                const float* __restrict__ W1,
                                float* __restrict__ XW, int N) {
    __shared__ float w[D * H];
    for (int i = threadIdx.x; i < D * H; i += blockDim.x) w[i] = W1[i];
    __syncthreads();
    int n = blockIdx.x * blockDim.x + threadIdx.x;
    if (n >= N) return;
    float acc[H];
#pragma unroll
    for (int j = 0; j < H; ++j) acc[j] = 0.f;
    const float4* xr = reinterpret_cast<const float4*>(X + (size_t)n * D);
#pragma unroll
    for (int d4 = 0; d4 < D / 4; ++d4) {
        float4 x = xr[d4];
        float xs[4] = {x.x, x.y, x.z, x.w};
#pragma unroll
        for (int k = 0; k < 4; ++k) {
            int d = d4 * 4 + k;
#pragma unroll
            for (int j = 0; j < H; ++j) acc[j] = fmaf(xs[k], w[d * H + j], acc[j]);
        }
    }
    float* o = XW + (size_t)n * HP;
#pragma unroll
    for (int j = 0; j < H; ++j) o[j] = acc[j];
    o[14] = 0.f; o[15] = 0.f;
}

// ---------------- CSR build: histogram -> scan -> scatter ------------------
__global__ void hist_kernel(const int* __restrict__ rows, int* __restrict__ counts, int E) {
    int e = blockIdx.x * blockDim.x + threadIdx.x;
    if (e < E) atomicAdd(&counts[rows[e]], 1);
}

__global__ void scanA_kernel(const int* __restrict__ counts, int* __restrict__ bsum, int N) {
    __shared__ int s[256];
    int i = blockIdx.x * 256 + threadIdx.x;
    s[threadIdx.x] = (i < N) ? counts[i] : 0;
    __syncthreads();
    for (int off = 128; off > 0; off >>= 1) {
        if (threadIdx.x < off) s[threadIdx.x] += s[threadIdx.x + off];
        __syncthreads();
    }
    if (threadIdx.x == 0) bsum[blockIdx.x] = s[0];
}

__global__ void scanB_kernel(const int* __restrict__ bsum, int* __restrict__ bex, int nb) {
    __shared__ int s[512];
    int tid = threadIdx.x;
    int v = (tid < nb) ? bsum[tid] : 0;
    s[tid] = v;
    __syncthreads();
    for (int off = 1; off < 512; off <<= 1) {
        int t = (tid >= off) ? s[tid - off] : 0;
        __syncthreads();
        s[tid] += t;
        __syncthreads();
    }
    if (tid < nb) bex[tid] = s[tid] - v; // exclusive prefix
}

__global__ void scanC_kernel(const int* __restrict__ counts, const int* __restrict__ bex,
                             int* __restrict__ row_start, int* __restrict__ cursor,
                             int N, int E) {
    __shared__ int s[256];
    int tid = threadIdx.x;
    int i = blockIdx.x * 256 + tid;
    int v = (i < N) ? counts[i] : 0;
    s[tid] = v;
    __syncthreads();
    for (int off = 1; off < 256; off <<= 1) {
        int t = (tid >= off) ? s[tid - off] : 0;
        __syncthreads();
        s[tid] += t;
        __syncthreads();
    }
    if (i < N) {
        int ex = bex[blockIdx.x] + s[tid] - v;
        row_start[i] = ex;
        cursor[i] = ex;
    }
    if (i == 0) row_start[N] = E;
}

__global__ void scatter_kernel(const int* __restrict__ rows, const int* __restrict__ cols,
                               const float* __restrict__ vals, int* __restrict__ cursor,
                               float2* __restrict__ epack, int E) {
    int e = blockIdx.x * blockDim.x + threadIdx.x;
    if (e >= E) return;
    int r = rows[e];
    int pos = atomicAdd(&cursor[r], 1);
    epack[pos] = make_float2(__int_as_float(cols[e]), vals[e]);
}

// ---------------- SpMM via CSR: 16 lanes per row, no atomics ---------------
__global__ void spmm_csr_kernel(const float* __restrict__ F,
                                const int* __restrict__ row_start,
                                const float2* __restrict__ epack,
                                float* __restrict__ Y, int N) {
    int t = blockIdx.x * blockDim.x + threadIdx.x;
    int r = t >> 4;
    int f = t & 15;
    if (r >= N) return;
    int beg = row_start[r];
    int end = row_start[r + 1];
    float acc = 0.f;
    for (int i = beg; i < end; ++i) {
        float2 p = epack[i];
        int c = __float_as_int(p.x);
        acc = fmaf(p.y, F[((size_t)c << 4) + f], acc);
    }
    Y[((size_t)r << 4) + f] = acc;
}

// ---------------- Dense: HW = relu(Y1) @ W2 (padded), (N,14)@(14,14) -------
__global__ void dense_hw_kernel(const float* __restrict__ Y1,
                                const float* __restrict__ W2,
                                float* __restrict__ HW, int N) {
    __shared__ float w[H * H];
    for (int i = threadIdx.x; i < H * H; i += blockDim.x) w[i] = W2[i];
    __syncthreads();
    int n = blockIdx.x * blockDim.x + threadIdx.x;
    if (n >= N) return;
    float h[H];
    const float* yr = Y1 + (size_t)n * HP;
#pragma unroll
    for (int i = 0; i < H; ++i) h[i] = fmaxf(yr[i], 0.f);
    float* o = HW + (size_t)n * HP;
#pragma unroll
    for (int j = 0; j < H; ++j) {
        float a = 0.f;
#pragma unroll
        for (int i = 0; i < H; ++i) a = fmaf(h[i], w[i * H + j], a);
        o[j] = a;
    }
    o[14] = 0.f; o[15] = 0.f;
}

// ---------------- Fused tail: h2=relu(Y2) -> tanh heads -> output ----------
__global__ void final_kernel(const float* __restrict__ Y2,
                             const float* __restrict__ Wd1,
                             const float* __restrict__ bd1,
                             const float* __restrict__ Wd2,
                             const float* __restrict__ bd2,
                             float* __restrict__ out, int N) {
    __shared__ float wd1[H * H], wd2[H * P], b1[H], b2[P];
    for (int i = threadIdx.x; i < H * H; i += blockDim.x) wd1[i] = Wd1[i];
    for (int i = threadIdx.x; i < H * P; i += blockDim.x) wd2[i] = Wd2[i];
    if (threadIdx.x < H) b1[threadIdx.x] = bd1[threadIdx.x];
    if (threadIdx.x < P) b2[threadIdx.x] = bd2[threadIdx.x];
    __syncthreads();
    int n = blockIdx.x * blockDim.x + threadIdx.x;
    if (n >= N) return;

    float h[H];
    const float* yr = Y2 + (size_t)n * HP;
#pragma unroll
    for (int i = 0; i < H; ++i) h[i] = fmaxf(yr[i], 0.f);

    float pd[H];
#pragma unroll
    for (int j = 0; j < H; ++j) {
        float a = b1[j];
#pragma unroll
        for (int i = 0; i < H; ++i) a = fmaf(h[i], wd1[i * H + j], a);
        pd[j] = tanhf(a);
    }

    float pp[P];
#pragma unroll
    for (int j = 0; j < P; ++j) {
        float a = b2[j];
#pragma unroll
        for (int i = 0; i < H; ++i) a = fmaf(h[i], wd2[i * P + j], a);
        pp[j] = tanhf(a);
    }

    float* o = out + (size_t)n * OUTW;
#pragma unroll
    for (int k = 0; k < LATc; ++k) o[k] = pd[k];
#pragma unroll
    for (int k = 0; k < LATc; ++k) {
        float x = pd[LATc + k] + SP_INV_1;
        o[LATc + k] = log1pf(expf(x)); // softplus
    }
#pragma unroll
    for (int k = 0; k < H; ++k) o[14 + k] = pp[k];
    o[28] = pp[14];
    o[29] = pp[15];
}

extern "C" void kernel_launch(void* const* d_in, const int* in_sizes, int n_in,
                              void* d_out, int out_size, void* d_ws, size_t ws_size,
                              hipStream_t stream) {
    const float* X    = (const float*)d_in[0];
    const int*   rows = (const int*)d_in[1];
    const int*   cols = (const int*)d_in[2];
    const float* vals = (const float*)d_in[3];
    const float* W1   = (const float*)d_in[4];
    const float* W2   = (const float*)d_in[5];
    const float* Wd1  = (const float*)d_in[6];
    const float* bd1  = (const float*)d_in[7];
    const float* Wd2  = (const float*)d_in[8];
    const float* bd2  = (const float*)d_in[9];
    float* out = (float*)d_out;

    const int N = in_sizes[0] / D;   // 100000
    const int E = in_sizes[1];       // 1000000
    const int nb = (N + 255) / 256;  // 391 scan blocks (<=512)

    // workspace layout:
    // XW16[N*16] | HW16[N*16] | Y116[N*16] | Y216[N*16] (floats)
    // | row_start[N+1] | cursor[N] | counts[N] | bsum[512] | bex[512] (ints)
    // | epack[E] (float2, 8B-aligned)
    float* XW = (float*)d_ws;
    float* HW = XW + (size_t)N * HP;
    float* Y1 = HW + (size_t)N * HP;
    float* Y2 = Y1 + (size_t)N * HP;
    int* row_start = (int*)(Y2 + (size_t)N * HP);
    int* cursor    = row_start + (N + 1);
    int* counts    = cursor + N;
    int* bsum      = counts + N;
    int* bex       = bsum + 512;
    // align epack to 8 bytes
    size_t ep_off = ((size_t)(bex + 512) + 7) & ~(size_t)7;
    float2* epack = (float2*)ep_off;

    hipMemsetAsync(counts, 0, (size_t)N * sizeof(int), stream);

    int blkE = (E + 255) / 256;
    int blkN = (N + 255) / 256;

    dense_xw_kernel<<<blkN, 256, 0, stream>>>(X, W1, XW, N);
    hist_kernel<<<blkE, 256, 0, stream>>>(rows, counts, E);
    scanA_kernel<<<nb, 256, 0, stream>>>(counts, bsum, N);
    scanB_kernel<<<1, 512, 0, stream>>>(bsum, bex, nb);
    scanC_kernel<<<nb, 256, 0, stream>>>(counts, bex, row_start, cursor, N, E);
    scatter_kernel<<<blkE, 256, 0, stream>>>(rows, cols, vals, cursor, epack, E);

    {
        long long threads = (long long)N * 16;
        unsigned grid = (unsigned)((threads + 255) / 256);
        spmm_csr_kernel<<<grid, 256, 0, stream>>>(XW, row_start, epack, Y1, N);
        dense_hw_kernel<<<blkN, 256, 0, stream>>>(Y1, W2, HW, N);
        spmm_csr_kernel<<<grid, 256, 0, stream>>>(HW, row_start, epack, Y2, N);
        final_kernel<<<blkN, 256, 0, stream>>>(Y2, Wd1, bd1, Wd2, bd2, out, N);
    }
}